// Round 14
// baseline (807.882 us; speedup 1.0000x reference)
//
#include <hip/hip_runtime.h>
#include <cmath>

#define NSN 50000
#define NTN 50000
#define EE  500000
#define NBE ((size_t)NSN * 128)
#define NPASS 2
#define PRNG 25000

using short8 = __attribute__((ext_vector_type(8))) short;
using f32x4  = __attribute__((ext_vector_type(4))) float;
#define MFMA16(a, b, c) __builtin_amdgcn_mfma_f32_16x16x32_bf16(a, b, c, 0, 0, 0)

__device__ __forceinline__ float  b2f(ushort u) { return __uint_as_float(((uint)u) << 16); }
__device__ __forceinline__ ushort f2b(float f) {
  uint x = __float_as_uint(f);
  uint r = x + 0x7FFFu + ((x >> 16) & 1u);
  return (ushort)(r >> 16);
}
__device__ __forceinline__ float blo(uint x) { return __uint_as_float(x << 16); }
__device__ __forceinline__ float bhi(uint x) { return __uint_as_float(x & 0xFFFF0000u); }
__device__ __forceinline__ uint  pk2(float a, float b) { return (uint)f2b(a) | ((uint)f2b(b) << 16); }

// ------------------------------------------------- all input/weight converts
__global__ void cvtall_k(const float* __restrict__ xs, const float* __restrict__ xt,
                         const float* __restrict__ wl,
                         const float* __restrict__ esw1, const float* __restrict__ esw2,
                         const float* __restrict__ etw1, const float* __restrict__ etw2,
                         ushort* __restrict__ xsB, ushort* __restrict__ xtB,
                         ushort* __restrict__ wlB, ushort* __restrict__ esw1B,
                         ushort* __restrict__ esw2B, ushort* __restrict__ etw1B,
                         ushort* __restrict__ etw2B) {
  int i = blockIdx.x * 256 + threadIdx.x;
  if (i < 3200000) { xsB[i] = f2b(xs[i]); return; }
  i -= 3200000;
  if (i < 3200000) {
    int r = i >> 6, k = i & 63;
    xtB[i] = (k < 48) ? f2b(xt[(size_t)r * 48 + k]) : (ushort)0;
    return;
  }
  i -= 3200000;
  if (i < 196608) { wlB[i] = f2b(wl[i]); return; }
  i -= 196608;
  if (i < 8192) { esw1B[i] = f2b(esw1[i]); return; }
  i -= 8192;
  if (i < 16384) { esw2B[i] = f2b(esw2[i]); return; }
  i -= 16384;
  if (i < 8192) {
    int r = i >> 6, k = i & 63;
    etw1B[i] = (k < 48) ? f2b(etw1[(size_t)r * 48 + k]) : (ushort)0;
    return;
  }
  i -= 8192;
  if (i < 16384) { etw2B[i] = f2b(etw2[i]); return; }
}

// ------------------------------------------------- combined wr + bias
__global__ void wrc_k(const float* __restrict__ wr, const float* __restrict__ bl,
                      ushort* __restrict__ wrcB, float* __restrict__ blc) {
  int z = blockIdx.y;
  int l = z >> 1, dd = z & 1;
  int r1 = dd ? 1 : 0, r2 = dd ? 2 : 3;
  int idx = blockIdx.x * 256 + threadIdx.x;
  if (idx < 16384) {
    wrcB[(size_t)z * 16384 + idx] =
        f2b(wr[(size_t)(l * 4 + r1) * 16384 + idx] + wr[(size_t)(l * 4 + r2) * 16384 + idx]);
    if (idx < 128)
      blc[z * 128 + idx] = bl[(l * 4 + r1) * 128 + idx] + bl[(l * 4 + r2) * 128 + idx];
  }
}

// ------------------------------------------------- head weight assembly
__global__ void headw_k(const float* __restrict__ gw1, const float* __restrict__ mw1,
                        const float* __restrict__ mw2, const float* __restrict__ gb1,
                        const float* __restrict__ mb1,
                        ushort* __restrict__ Whead, float* __restrict__ biasHead,
                        ushort* __restrict__ w1eB, ushort* __restrict__ w2B) {
  int idx = blockIdx.x * 256 + threadIdx.x;
  if (idx < 65536) {
    int z = idx >> 15, rr = (idx >> 7) & 255, c = idx & 127;
    float v = (rr < 128) ? gw1[(size_t)rr * 256 + z * 128 + c]
                         : mw1[(size_t)(rr - 128) * 160 + c];
    Whead[idx] = f2b(v);
  } else if (idx < 69632) {
    int i = idx - 65536;
    w1eB[i] = f2b(mw1[(size_t)(i >> 5) * 160 + 128 + (i & 31)]);
  } else if (idx < 77824) {
    int i = idx - 69632;
    w2B[i] = f2b(mw2[i]);
  } else if (idx < 78336) {
    int i = idx - 77824;
    int z = i >> 8, n = i & 255;
    biasHead[i] = (n < 128) ? (z ? 0.f : gb1[n]) : mb1[n - 128];
  }
}

// --------------------------------------------------------------- CSR build
__global__ void count4_k(const int* __restrict__ e0, const int* __restrict__ e1,
                         const int* __restrict__ e2, const int* __restrict__ e3,
                         int* __restrict__ cnt) {
  int rel = blockIdx.y;
  const int* col = (rel == 0 ? e0 : rel == 1 ? e1 : rel == 2 ? e2 : e3) + EE;
  int i = blockIdx.x * 256 + threadIdx.x;
  if (i < EE) atomicAdd(&cnt[rel * 50000 + col[i]], 1);
}

// hierarchical scan
__global__ __launch_bounds__(256) void scanA_k(const int* __restrict__ cnt,
                                               int* __restrict__ loc,
                                               int* __restrict__ bsum) {
  __shared__ int ws[4];
  int rel = blockIdx.y, b = blockIdx.x, t = threadIdx.x;
  const int* c = cnt + (size_t)rel * 50000;
  int base = b * 2048 + t * 8;
  int v[8], s = 0;
  #pragma unroll
  for (int i = 0; i < 8; ++i) {
    int idx = base + i;
    v[i] = (idx < 50000) ? c[idx] : 0;
    s += v[i];
  }
  int lane = t & 63, w = t >> 6;
  int x = s;
  #pragma unroll
  for (int d = 1; d < 64; d <<= 1) {
    int y = __shfl_up(x, d, 64);
    if (lane >= d) x += y;
  }
  if (lane == 63) ws[w] = x;
  __syncthreads();
  int add = 0;
  for (int ww = 0; ww < w; ++ww) add += ws[ww];
  int run = add + x - s;
  #pragma unroll
  for (int i = 0; i < 8; ++i) {
    int idx = base + i;
    run += v[i];
    if (idx < 50000) loc[(size_t)rel * 50000 + idx] = run;
  }
  if (t == 255) bsum[rel * 25 + b] = add + x;
}
__global__ void scanB_k(int* __restrict__ bsum) {
  int t = threadIdx.x;
  if (t < 4) {
    int s = 0;
    for (int b = 0; b < 25; ++b) {
      int v = bsum[t * 25 + b];
      bsum[t * 25 + b] = s;
      s += v;
    }
  }
}
// scanC also expands rel-2 per-position col (folded colof)
__global__ void scanC_k(const int* __restrict__ cnt, const int* __restrict__ loc,
                        const int* __restrict__ bsum, int* __restrict__ off,
                        int* __restrict__ cur, int* __restrict__ colOf) {
  int rel = blockIdx.y;
  int i = blockIdx.x * 256 + threadIdx.x;
  if (i < 50000) {
    int incl = loc[(size_t)rel * 50000 + i] + bsum[rel * 25 + i / 2048];
    int cntv = cnt[(size_t)rel * 50000 + i];
    off[(size_t)rel * 50001 + i + 1] = incl;
    cur[(size_t)rel * 50000 + i] = incl - cntv;
    if (i == 0) off[(size_t)rel * 50001] = 0;
    if (rel == 2) {
      for (int k = incl - cntv; k < incl; ++k) colOf[k] = i;
    }
  }
}

// range-partitioned fill; rel 2 also records original edge id
__global__ void fillP_k(const int* __restrict__ e0, const int* __restrict__ e1,
                        const int* __restrict__ e2, const int* __restrict__ e3,
                        int* __restrict__ cur, int* __restrict__ adj,
                        int* __restrict__ adjE, int pass) {
  int rel = blockIdx.y;
  const int* ei = rel == 0 ? e0 : rel == 1 ? e1 : rel == 2 ? e2 : e3;
  int e = blockIdx.x * 256 + threadIdx.x;
  if (e < EE) {
    int c = ei[EE + e];
    if (c >= pass * PRNG && c < (pass + 1) * PRNG) {
      int pos = atomicAdd(&cur[rel * 50000 + c], 1);
      adj[(size_t)rel * EE + pos] = ei[e];
      if (rel == 2) adjE[pos] = e;
    }
  }
}

// -------------------------------- permute ea into CSR order (+bf16 convert)
__global__ void eaperm_k(const float* __restrict__ ea, const int* __restrict__ adjE,
                         ushort* __restrict__ eaB, int E) {
  int idx = blockIdx.x * 256 + threadIdx.x;
  int pos = idx >> 3, q = idx & 7;
  if (pos < E) {
    int eid = adjE[pos];
    float4 v = *(const float4*)(ea + (size_t)eid * 32 + q * 4);
    ushort4 o;
    o.x = f2b(v.x); o.y = f2b(v.y); o.z = f2b(v.z); o.w = f2b(v.w);
    *(ushort4*)(eaB + (size_t)pos * 32 + q * 4) = o;
  }
}

// ------------------------------------------------------------- gather-mean
__global__ __launch_bounds__(256) void gather4_k(
    const ushort* __restrict__ hs, const ushort* __restrict__ ht,
    const int* __restrict__ off4, const int* __restrict__ adj4,
    ushort* __restrict__ m0, ushort* __restrict__ m1,
    ushort* __restrict__ m2, ushort* __restrict__ m3, int N) {
  int r = blockIdx.y;
  const ushort* src = (r == 0 || r == 2) ? hs : ht;
  ushort* dst = r == 0 ? m0 : (r == 1 ? m1 : (r == 2 ? m2 : m3));
  const int* off = off4 + r * 50001;
  const int* adj = adj4 + (size_t)r * EE;
  int t = threadIdx.x;
  int n = blockIdx.x * 4 + (t >> 6);
  if (n >= N) return;
  int lane = t & 63, g = lane >> 4, i = lane & 15;
  int s = off[n], e = off[n + 1];
  float a[8] = {};
  int k = s + g;
  for (; k + 4 < e; k += 8) {
    int r0 = adj[k], r1 = adj[k + 4];
    uint4 v0 = *(const uint4*)(src + (size_t)r0 * 128 + i * 8);
    uint4 v1 = *(const uint4*)(src + (size_t)r1 * 128 + i * 8);
    a[0] += blo(v0.x) + blo(v1.x); a[1] += bhi(v0.x) + bhi(v1.x);
    a[2] += blo(v0.y) + blo(v1.y); a[3] += bhi(v0.y) + bhi(v1.y);
    a[4] += blo(v0.z) + blo(v1.z); a[5] += bhi(v0.z) + bhi(v1.z);
    a[6] += blo(v0.w) + blo(v1.w); a[7] += bhi(v0.w) + bhi(v1.w);
  }
  if (k < e) {
    int r0 = adj[k];
    uint4 v = *(const uint4*)(src + (size_t)r0 * 128 + i * 8);
    a[0] += blo(v.x); a[1] += bhi(v.x);
    a[2] += blo(v.y); a[3] += bhi(v.y);
    a[4] += blo(v.z); a[5] += bhi(v.z);
    a[6] += blo(v.w); a[7] += bhi(v.w);
  }
  #pragma unroll
  for (int c = 0; c < 8; ++c) {
    a[c] += __shfl_xor(a[c], 16, 64);
    a[c] += __shfl_xor(a[c], 32, 64);
  }
  if (g == 0) {
    float inv = 1.f / (float)max(e - s, 1);
    uint4 o;
    o.x = pk2(a[0] * inv, a[1] * inv);
    o.y = pk2(a[2] * inv, a[3] * inv);
    o.z = pk2(a[4] * inv, a[5] * inv);
    o.w = pk2(a[6] * inv, a[7] * inv);
    *(uint4*)(dst + (size_t)n * 128 + i * 8) = o;
  }
}

// ------------------------------------------------------- shared GEMM body
template <int MODE>
__device__ __forceinline__ void gemm_body(
    ushort (*As)[40], ushort (*Ws)[40],
    const ushort* __restrict__ A, const ushort* __restrict__ W,
    const float* __restrict__ bias, ushort* __restrict__ C,
    int M, int K, int ldc, int m0) {
  int t = threadIdx.x;
  int lane = t & 63, w = t >> 6, wm = w >> 1, wn = w & 1;
  f32x4 zz = {0.f, 0.f, 0.f, 0.f};
  f32x4 acc[4][4];
  #pragma unroll
  for (int i = 0; i < 4; ++i)
    #pragma unroll
    for (int j = 0; j < 4; ++j) acc[i][j] = zz;
  for (int kb = 0; kb < K; kb += 32) {
    #pragma unroll
    for (int s = 0; s < 2; ++s) {
      int idx = t + s * 256;
      int r = idx >> 2, c = idx & 3;
      int gm = m0 + r;
      uint4 va = make_uint4(0, 0, 0, 0);
      if (gm < M) va = *(const uint4*)(A + (size_t)gm * K + kb + c * 8);
      *(uint4*)&As[r][c * 8] = va;
      *(uint4*)&Ws[r][c * 8] = *(const uint4*)(W + (size_t)r * K + kb + c * 8);
    }
    __syncthreads();
    short8 af[4], bf[4];
    #pragma unroll
    for (int mf = 0; mf < 4; ++mf)
      af[mf] = *(const short8*)&As[wm * 64 + mf * 16 + (lane & 15)][(lane >> 4) * 8];
    #pragma unroll
    for (int nf = 0; nf < 4; ++nf)
      bf[nf] = *(const short8*)&Ws[wn * 64 + nf * 16 + (lane & 15)][(lane >> 4) * 8];
    #pragma unroll
    for (int mf = 0; mf < 4; ++mf)
      #pragma unroll
      for (int nf = 0; nf < 4; ++nf) acc[mf][nf] = MFMA16(af[mf], bf[nf], acc[mf][nf]);
    __syncthreads();
  }
  int r0 = (lane >> 4) * 4, nin = lane & 15;
  #pragma unroll
  for (int mf = 0; mf < 4; ++mf)
    #pragma unroll
    for (int nf = 0; nf < 4; ++nf) {
      int n = wn * 64 + nf * 16 + nin;
      float bv = bias ? bias[n] : 0.f;
      #pragma unroll
      for (int i = 0; i < 4; ++i) {
        int gm = m0 + wm * 64 + mf * 16 + r0 + i;
        if (gm >= M) continue;
        float v = acc[mf][nf][i] + bv;
        if (MODE == 1) v = fmaxf(v, 0.f);
        C[(size_t)gm * ldc + n] = f2b(v);
      }
    }
}

// -------------------------------- fused 2-layer encoder (h1 kept in LDS)
__global__ __launch_bounds__(256) void encf_k(
    const ushort* __restrict__ A0, const ushort* __restrict__ A1,
    const ushort* __restrict__ W10, const ushort* __restrict__ W11,
    const ushort* __restrict__ W20, const ushort* __restrict__ W21,
    const float* __restrict__ b10, const float* __restrict__ b11,
    const float* __restrict__ b20, const float* __restrict__ b21,
    ushort* __restrict__ C0, ushort* __restrict__ C1, int M) {
  __shared__ alignas(16) ushort As[128][40];
  __shared__ alignas(16) ushort Ws[128][40];
  __shared__ alignas(16) ushort H1[128][136];
  int y = blockIdx.y;
  const ushort* A  = y ? A1 : A0;
  const ushort* W1 = y ? W11 : W10;
  const ushort* W2 = y ? W21 : W20;
  const float* b1 = y ? b11 : b10;
  const float* b2 = y ? b21 : b20;
  ushort* C = y ? C1 : C0;
  int t = threadIdx.x;
  int m0 = blockIdx.x * 128;
  int lane = t & 63, w = t >> 6, wm = w >> 1, wn = w & 1;
  f32x4 zz = {0.f, 0.f, 0.f, 0.f};
  f32x4 acc[4][4];
  #pragma unroll
  for (int i = 0; i < 4; ++i)
    #pragma unroll
    for (int j = 0; j < 4; ++j) acc[i][j] = zz;
  for (int kb = 0; kb < 64; kb += 32) {
    #pragma unroll
    for (int s = 0; s < 2; ++s) {
      int idx = t + s * 256;
      int r = idx >> 2, c = idx & 3;
      int gm = m0 + r;
      uint4 va = make_uint4(0, 0, 0, 0);
      if (gm < M) va = *(const uint4*)(A + (size_t)gm * 64 + kb + c * 8);
      *(uint4*)&As[r][c * 8] = va;
      *(uint4*)&Ws[r][c * 8] = *(const uint4*)(W1 + (size_t)r * 64 + kb + c * 8);
    }
    __syncthreads();
    short8 af[4], bf[4];
    #pragma unroll
    for (int mf = 0; mf < 4; ++mf)
      af[mf] = *(const short8*)&As[wm * 64 + mf * 16 + (lane & 15)][(lane >> 4) * 8];
    #pragma unroll
    for (int nf = 0; nf < 4; ++nf)
      bf[nf] = *(const short8*)&Ws[wn * 64 + nf * 16 + (lane & 15)][(lane >> 4) * 8];
    #pragma unroll
    for (int mf = 0; mf < 4; ++mf)
      #pragma unroll
      for (int nf = 0; nf < 4; ++nf) acc[mf][nf] = MFMA16(af[mf], bf[nf], acc[mf][nf]);
    __syncthreads();
  }
  {
    int r0 = (lane >> 4) * 4, nin = lane & 15;
    #pragma unroll
    for (int mf = 0; mf < 4; ++mf)
      #pragma unroll
      for (int nf = 0; nf < 4; ++nf) {
        int n = wn * 64 + nf * 16 + nin;
        float bv = b1[n];
        #pragma unroll
        for (int i = 0; i < 4; ++i)
          H1[wm * 64 + mf * 16 + r0 + i][n] = f2b(fmaxf(acc[mf][nf][i] + bv, 0.f));
      }
  }
  __syncthreads();
  #pragma unroll
  for (int i = 0; i < 4; ++i)
    #pragma unroll
    for (int j = 0; j < 4; ++j) acc[i][j] = zz;
  for (int kb = 0; kb < 128; kb += 32) {
    #pragma unroll
    for (int s = 0; s < 2; ++s) {
      int idx = t + s * 256;
      int r = idx >> 2, c = idx & 3;
      *(uint4*)&Ws[r][c * 8] = *(const uint4*)(W2 + (size_t)r * 128 + kb + c * 8);
    }
    __syncthreads();
    short8 af[4], bf[4];
    #pragma unroll
    for (int mf = 0; mf < 4; ++mf)
      af[mf] = *(const short8*)&H1[wm * 64 + mf * 16 + (lane & 15)][kb + (lane >> 4) * 8];
    #pragma unroll
    for (int nf = 0; nf < 4; ++nf)
      bf[nf] = *(const short8*)&Ws[wn * 64 + nf * 16 + (lane & 15)][(lane >> 4) * 8];
    #pragma unroll
    for (int mf = 0; mf < 4; ++mf)
      #pragma unroll
      for (int nf = 0; nf < 4; ++nf) acc[mf][nf] = MFMA16(af[mf], bf[nf], acc[mf][nf]);
    __syncthreads();
  }
  {
    int r0 = (lane >> 4) * 4, nin = lane & 15;
    #pragma unroll
    for (int mf = 0; mf < 4; ++mf)
      #pragma unroll
      for (int nf = 0; nf < 4; ++nf) {
        int n = wn * 64 + nf * 16 + nin;
        float bv = b2[n];
        #pragma unroll
        for (int i = 0; i < 4; ++i) {
          int gm = m0 + wm * 64 + mf * 16 + r0 + i;
          if (gm >= M) continue;
          C[(size_t)gm * 128 + n] = f2b(acc[mf][nf][i] + bv);
        }
      }
  }
}

__global__ __launch_bounds__(256) void gemmH_k(
    const ushort* Abase, const ushort* Whead, const float* biasHead,
    ushort* pS, ushort* pT) {
  __shared__ alignas(16) ushort As[128][40];
  __shared__ alignas(16) ushort Ws[128][40];
  int z = blockIdx.z, ny = blockIdx.y;
  gemm_body<0>(As, Ws, Abase + (size_t)z * NBE,
               Whead + ((size_t)z * 256 + ny * 128) * 128,
               biasHead + z * 256 + ny * 128,
               (z ? pT : pS) + ny * 128,
               NSN, 128, 256, blockIdx.x * 128);
}

// ---------------------------------- layer GEMM: 3 A-panels, both dst types
template <int RES>
__global__ __launch_bounds__(256) void lgemm_k(
    const ushort* __restrict__ hs, const ushort* __restrict__ ht,
    const ushort* __restrict__ m0, const ushort* __restrict__ m1,
    const ushort* __restrict__ m2, const ushort* __restrict__ m3,
    const ushort* __restrict__ wlL, const ushort* __restrict__ wrcL,
    const float* __restrict__ blcL,
    ushort* __restrict__ hsOut, ushort* __restrict__ htOut, int M) {
  __shared__ alignas(16) ushort As[128][40];
  __shared__ alignas(16) ushort Ws[128][40];
  int t = threadIdx.x;
  int y = blockIdx.y;
  int m0i = blockIdx.x * 128;
  const ushort* A0 = y ? m1 : m0;
  const ushort* A1 = y ? m2 : m3;
  const ushort* self = y ? ht : hs;
  const ushort* W0 = wlL + (size_t)(y ? 1 : 0) * 16384;
  const ushort* W1 = wlL + (size_t)(y ? 2 : 3) * 16384;
  const ushort* W2 = wrcL + (size_t)y * 16384;
  const float* bias = blcL + y * 128;
  ushort* C = y ? htOut : hsOut;

  int lane = t & 63, w = t >> 6, wm = w >> 1, wn = w & 1;
  f32x4 zz = {0.f, 0.f, 0.f, 0.f};
  f32x4 acc[4][4];
  #pragma unroll
  for (int i = 0; i < 4; ++i)
    #pragma unroll
    for (int j = 0; j < 4; ++j) acc[i][j] = zz;
  for (int p = 0; p < 3; ++p) {
    const ushort* A = p == 0 ? A0 : (p == 1 ? A1 : self);
    const ushort* Wp = p == 0 ? W0 : (p == 1 ? W1 : W2);
    for (int kb = 0; kb < 128; kb += 32) {
      #pragma unroll
      for (int s = 0; s < 2; ++s) {
        int idx = t + s * 256;
        int r = idx >> 2, c = idx & 3;
        int gm = m0i + r;
        uint4 va = make_uint4(0, 0, 0, 0);
        if (gm < M) va = *(const uint4*)(A + (size_t)gm * 128 + kb + c * 8);
        *(uint4*)&As[r][c * 8] = va;
        *(uint4*)&Ws[r][c * 8] = *(const uint4*)(Wp + (size_t)r * 128 + kb + c * 8);
      }
      __syncthreads();
      short8 af[4], bf[4];
      #pragma unroll
      for (int mf = 0; mf < 4; ++mf)
        af[mf] = *(const short8*)&As[wm * 64 + mf * 16 + (lane & 15)][(lane >> 4) * 8];
      #pragma unroll
      for (int nf = 0; nf < 4; ++nf)
        bf[nf] = *(const short8*)&Ws[wn * 64 + nf * 16 + (lane & 15)][(lane >> 4) * 8];
      #pragma unroll
      for (int mf = 0; mf < 4; ++mf)
        #pragma unroll
        for (int nf = 0; nf < 4; ++nf) acc[mf][nf] = MFMA16(af[mf], bf[nf], acc[mf][nf]);
      __syncthreads();
    }
  }
  int r0 = (lane >> 4) * 4, nin = lane & 15;
  #pragma unroll
  for (int mf = 0; mf < 4; ++mf)
    #pragma unroll
    for (int nf = 0; nf < 4; ++nf) {
      int n = wn * 64 + nf * 16 + nin;
      float bv = bias[n];
      #pragma unroll
      for (int i = 0; i < 4; ++i) {
        int gm = m0i + wm * 64 + mf * 16 + r0 + i;
        if (gm >= M) continue;
        float v = 0.5f * (acc[mf][nf][i] + bv);
        if (RES) v += b2f(self[(size_t)gm * 128 + n]);
        C[(size_t)gm * 128 + n] = f2b(fmaxf(v, 0.f));
      }
    }
}

// ---------------------------------------------------------------- edge head
// Barrier-free: each wave owns an independent 16-edge tile; all phases
// wave-local (LDS slice per wave, intra-wave RAW needs no __syncthreads).
__global__ __launch_bounds__(256) void head_k(
    const ushort* __restrict__ pS, const ushort* __restrict__ pT,
    const int* __restrict__ erowA, const int* __restrict__ ecolA,
    const int* __restrict__ eidA, const ushort* __restrict__ eaB,
    const ushort* __restrict__ w1eB, const ushort* __restrict__ w2B,
    const float* __restrict__ gw2, const float* __restrict__ gb2p,
    const float* __restrict__ mb2, const float* __restrict__ mw3,
    const float* __restrict__ mb3, float* __restrict__ out, int E) {
  __shared__ alignas(16) ushort h1w[4][16][136];   // per-wave h1 tile
  __shared__ alignas(16) float gw2s[128];
  __shared__ alignas(16) float mw3s[128];
  __shared__ float mb2s[64];

  // bijective XCD swizzle
  int nwg = gridDim.x;
  int bid = blockIdx.x;
  int q = nwg >> 3, r = nwg & 7;
  int xcd = bid & 7, sub = bid >> 3;
  int swz = (xcd < r ? xcd * (q + 1) : r * (q + 1) + (xcd - r) * q) + sub;
  int e0 = swz * 64;

  int t = threadIdx.x;
  if (t < 128) gw2s[t] = gw2[t];
  else mw3s[t - 128] = mw3[t - 128];
  if (t < 64) mb2s[t] = mb2[t];
  __syncthreads();   // the only block-wide barrier (weight staging)

  int lane = t & 63, w = t >> 6;
  int ew0 = e0 + w * 16;   // this wave's 16 edges
  float gb2v = gb2p[0];

  // Phase E: eat = ea @ w1e^T (M=16, N=128, K=32) -> h1w[w]
  {
    int p = ew0 + (lane & 15);
    short8 a = {};
    if (p < E) a = *(const short8*)(eaB + (size_t)p * 32 + (lane >> 4) * 8);
    int ebase = (lane >> 4) * 4;
    #pragma unroll
    for (int nf = 0; nf < 8; ++nf) {
      short8 b = *(const short8*)(w1eB + (size_t)(nf * 16 + (lane & 15)) * 32 + (lane >> 4) * 8);
      f32x4 cz = {0.f, 0.f, 0.f, 0.f};
      cz = MFMA16(a, b, cz);
      int jj = nf * 16 + (lane & 15);
      #pragma unroll
      for (int i = 0; i < 4; ++i) h1w[w][ebase + i][jj] = f2b(cz[i]);
    }
  }
  // Phase G: gate + convex combine + eat RMW + relu (4 lanes per edge)
  {
    int el = lane >> 2, qq = lane & 3;
    int p = ew0 + el;
    int row = (p < E) ? erowA[p] : 0;
    int col = (p < E) ? ecolA[p] : 0;
    const ushort* ps = pS + (size_t)row * 256;
    const ushort* pt = pT + (size_t)col * 256;
    int j0 = qq * 32;
    float dot = 0.f;
    #pragma unroll
    for (int cc = 0; cc < 4; ++cc) {
      int j = j0 + cc * 8;
      uint4 ga = *(const uint4*)(ps + j);
      uint4 gb = *(const uint4*)(pt + j);
      const float* gp = &gw2s[j];
      float h;
      h = fmaxf(blo(ga.x) + blo(gb.x), 0.f); dot = fmaf(h, gp[0], dot);
      h = fmaxf(bhi(ga.x) + bhi(gb.x), 0.f); dot = fmaf(h, gp[1], dot);
      h = fmaxf(blo(ga.y) + blo(gb.y), 0.f); dot = fmaf(h, gp[2], dot);
      h = fmaxf(bhi(ga.y) + bhi(gb.y), 0.f); dot = fmaf(h, gp[3], dot);
      h = fmaxf(blo(ga.z) + blo(gb.z), 0.f); dot = fmaf(h, gp[4], dot);
      h = fmaxf(bhi(ga.z) + bhi(gb.z), 0.f); dot = fmaf(h, gp[5], dot);
      h = fmaxf(blo(ga.w) + blo(gb.w), 0.f); dot = fmaf(h, gp[6], dot);
      h = fmaxf(bhi(ga.w) + bhi(gb.w), 0.f); dot = fmaf(h, gp[7], dot);
    }
    dot += __shfl_xor(dot, 1, 64);
    dot += __shfl_xor(dot, 2, 64);
    float g = 1.f / (1.f + __expf(-(dot + gb2v)));
    float om = 1.f - g;
    #pragma unroll
    for (int cc = 0; cc < 4; ++cc) {
      int j = j0 + cc * 8;
      uint4 uu = *(const uint4*)(ps + 128 + j);
      uint4 vv = *(const uint4*)(pt + 128 + j);
      uint4 ee = *(const uint4*)&h1w[w][el][j];
      uint o0 = pk2(fmaxf(fmaf(g, blo(uu.x), om * blo(vv.x)) + blo(ee.x), 0.f),
                    fmaxf(fmaf(g, bhi(uu.x), om * bhi(vv.x)) + bhi(ee.x), 0.f));
      uint o1 = pk2(fmaxf(fmaf(g, blo(uu.y), om * blo(vv.y)) + blo(ee.y), 0.f),
                    fmaxf(fmaf(g, bhi(uu.y), om * bhi(vv.y)) + bhi(ee.y), 0.f));
      uint o2 = pk2(fmaxf(fmaf(g, blo(uu.z), om * blo(vv.z)) + blo(ee.z), 0.f),
                    fmaxf(fmaf(g, bhi(uu.z), om * bhi(vv.z)) + bhi(ee.z), 0.f));
      uint o3 = pk2(fmaxf(fmaf(g, blo(uu.w), om * blo(vv.w)) + blo(ee.w), 0.f),
                    fmaxf(fmaf(g, bhi(uu.w), om * bhi(vv.w)) + bhi(ee.w), 0.f));
      *(uint4*)&h1w[w][el][j] = make_uint4(o0, o1, o2, o3);
    }
  }
  // Phase H: h2 = relu(h1 @ w2^T + b2)  (M=16, N=64, K=128), wave-local
  f32x4 hacc[4];
  {
    f32x4 zz = {0.f, 0.f, 0.f, 0.f};
    #pragma unroll
    for (int nf = 0; nf < 4; ++nf) hacc[nf] = zz;
    #pragma unroll
    for (int ks = 0; ks < 4; ++ks) {
      short8 a = *(const short8*)&h1w[w][lane & 15][ks * 32 + (lane >> 4) * 8];
      #pragma unroll
      for (int nf = 0; nf < 4; ++nf) {
        short8 b = *(const short8*)(w2B + (size_t)(nf * 16 + (lane & 15)) * 128 + ks * 32 + (lane >> 4) * 8);
        hacc[nf] = MFMA16(a, b, hacc[nf]);
      }
    }
  }
  // Phase O: out = h2 @ mw3^T + b3, in-register 16-lane reduce
  {
    float part[4][2];
    #pragma unroll
    for (int i = 0; i < 4; ++i) {
      #pragma unroll
      for (int o = 0; o < 2; ++o) {
        float s = 0.f;
        #pragma unroll
        for (int nf = 0; nf < 4; ++nf) {
          float h2v = fmaxf(hacc[nf][i] + mb2s[nf * 16 + (lane & 15)], 0.f);
          s = fmaf(h2v, mw3s[o * 64 + nf * 16 + (lane & 15)], s);
        }
        part[i][o] = s;
      }
    }
    #pragma unroll
    for (int i = 0; i < 4; ++i)
      #pragma unroll
      for (int o = 0; o < 2; ++o) {
        float s = part[i][o];
        s += __shfl_xor(s, 1, 64);
        s += __shfl_xor(s, 2, 64);
        s += __shfl_xor(s, 4, 64);
        s += __shfl_xor(s, 8, 64);
        part[i][o] = s;
      }
    if ((lane & 15) == 0) {
      int ebase = (lane >> 4) * 4;
      float b30 = mb3[0], b31 = mb3[1];
      #pragma unroll
      for (int i = 0; i < 4; ++i) {
        int p = ew0 + ebase + i;
        if (p < E) {
          int eid = eidA[p];
          out[(size_t)eid * 2 + 0] = part[i][0] + b30;
          out[(size_t)eid * 2 + 1] = part[i][1] + b31;
        }
      }
    }
  }
}

// ------------------------------------------------------------------- launch
extern "C" void kernel_launch(void* const* d_in, const int* in_sizes, int n_in,
                              void* d_out, int out_size, void* d_ws, size_t ws_size,
                              hipStream_t stream) {
  const float* x_source = (const float*)d_in[0];
  const float* x_target = (const float*)d_in[1];
  const float* edge_attr = (const float*)d_in[2];
  const float* enc_s_w1 = (const float*)d_in[3];
  const float* enc_s_b1 = (const float*)d_in[4];
  const float* enc_s_w2 = (const float*)d_in[5];
  const float* enc_s_b2 = (const float*)d_in[6];
  const float* enc_t_w1 = (const float*)d_in[7];
  const float* enc_t_b1 = (const float*)d_in[8];
  const float* enc_t_w2 = (const float*)d_in[9];
  const float* enc_t_b2 = (const float*)d_in[10];
  const float* conv_wl = (const float*)d_in[11];
  const float* conv_bl = (const float*)d_in[12];
  const float* conv_wr = (const float*)d_in[13];
  const float* gate_w1 = (const float*)d_in[14];
  const float* gate_b1 = (const float*)d_in[15];
  const float* gate_w2 = (const float*)d_in[16];
  const float* gate_b2 = (const float*)d_in[17];
  const float* mlp_w1 = (const float*)d_in[18];
  const float* mlp_b1 = (const float*)d_in[19];
  const float* mlp_w2 = (const float*)d_in[20];
  const float* mlp_b2 = (const float*)d_in[21];
  const float* mlp_w3 = (const float*)d_in[22];
  const float* mlp_b3 = (const float*)d_in[23];
  const int* ei[4] = {(const int*)d_in[24], (const int*)d_in[25],
                      (const int*)d_in[26], (const int*)d_in[27]};  // 0=ss,1=tt,2=st,3=ts
  float* out = (float*)d_out;

  char* wsp = (char*)d_ws;
  size_t off = 0;
  auto alloc = [&](size_t bytes) {
    char* p = wsp + off;
    off += (bytes + 255) & ~(size_t)255;
    return p;
  };
  ushort* nbase = (ushort*)alloc(4 * NBE * 2);
  ushort* nb[4];
  for (int i = 0; i < 4; ++i) nb[i] = nbase + (size_t)i * NBE;
  ushort* shared4 = (ushort*)alloc(4 * NBE * 2);
  ushort* mB[4];
  for (int i = 0; i < 4; ++i) mB[i] = shared4 + (size_t)i * NBE;
  int* adj4 = (int*)alloc((size_t)4 * EE * 4);
  int* off4 = (int*)alloc(4 * 50001 * 4);
  int* cur4 = (int*)alloc(4 * 50000 * 4);
  int* cnt4 = (int*)alloc(4 * 50000 * 4);
  int* bsum = (int*)alloc(128 * 4);
  ushort* xsB = (ushort*)alloc((size_t)NSN * 64 * 2);   // dead after encf -> adjE
  ushort* xtB = (ushort*)alloc((size_t)NTN * 64 * 2);   // dead after encf -> colOf
  ushort* esw1B = (ushort*)alloc(128 * 64 * 2);
  ushort* esw2B = (ushort*)alloc(128 * 128 * 2);
  ushort* etw1B = (ushort*)alloc(128 * 64 * 2);
  ushort* etw2B = (ushort*)alloc(128 * 128 * 2);
  ushort* wlB = (ushort*)alloc((size_t)12 * 16384 * 2);
  ushort* wrcB = (ushort*)alloc((size_t)6 * 16384 * 2);
  float* blc = (float*)alloc(6 * 128 * 4);
  ushort* Whead = (ushort*)alloc((size_t)2 * 256 * 128 * 2);
  float* biasHead = (float*)alloc(2 * 256 * 4);
  ushort* w1eB = (ushort*)alloc(128 * 32 * 2);
  ushort* w2B = (ushort*)alloc(64 * 128 * 2);

  // --- conversions / weight assembly / fused encoders (frees xsB/xtB) ---
  cvtall_k<<<(6645760 + 255) / 256, 256, 0, stream>>>(
      x_source, x_target, conv_wl, enc_s_w1, enc_s_w2, enc_t_w1, enc_t_w2,
      xsB, xtB, wlB, esw1B, esw2B, etw1B, etw2B);
  wrc_k<<<dim3(64, 6), 256, 0, stream>>>(conv_wr, conv_bl, wrcB, blc);
  headw_k<<<307, 256, 0, stream>>>(gate_w1, mlp_w1, mlp_w2, gate_b1, mlp_b1,
                                   Whead, biasHead, w1eB, w2B);
  int gm = (NSN + 127) / 128;
  encf_k<<<dim3(gm, 2), 256, 0, stream>>>(xsB, xtB, esw1B, etw1B, esw2B, etw2B,
      enc_s_b1, enc_t_b1, enc_s_b2, enc_t_b2, nb[0], nb[1], NSN);

  // --- CSR build (adjE/colOf overlay dead xsB/xtB) ---
  int* adjE = (int*)xsB;
  int* colOf = (int*)xtB;
  hipMemsetAsync(cnt4, 0, 4 * 50000 * sizeof(int), stream);
  int cb = (EE + 255) / 256;
  count4_k<<<dim3(cb, 4), 256, 0, stream>>>(ei[0], ei[1], ei[2], ei[3], cnt4);
  scanA_k<<<dim3(25, 4), 256, 0, stream>>>(cnt4, cur4, bsum);
  scanB_k<<<1, 64, 0, stream>>>(bsum);
  scanC_k<<<dim3((50000 + 255) / 256, 4), 256, 0, stream>>>(cnt4, cur4, bsum, off4,
                                                            cur4, colOf);
  for (int p = 0; p < NPASS; ++p)
    fillP_k<<<dim3(cb, 4), 256, 0, stream>>>(ei[0], ei[1], ei[2], ei[3], cur4, adj4, adjE, p);

  // --- 3 hetero layers: (0,1)->(2,3)->(0,1)->(2,3) ---
  int gb = (NSN + 3) / 4;
  {
    gather4_k<<<dim3(gb, 4), 256, 0, stream>>>(nb[0], nb[1], off4, adj4,
        mB[0], mB[1], mB[2], mB[3], NSN);
    lgemm_k<0><<<dim3(gm, 2), 256, 0, stream>>>(nb[0], nb[1],
        mB[0], mB[1], mB[2], mB[3], wlB, wrcB, blc, nb[2], nb[3], NSN);
    gather4_k<<<dim3(gb, 4), 256, 0, stream>>>(nb[2], nb[3], off4, adj4,
        mB[0], mB[1], mB[2], mB[3], NSN);
    lgemm_k<1><<<dim3(gm, 2), 256, 0, stream>>>(nb[2], nb[3],
        mB[0], mB[1], mB[2], mB[3], wlB + (size_t)4 * 16384,
        wrcB + (size_t)2 * 16384, blc + 256, nb[0], nb[1], NSN);
    gather4_k<<<dim3(gb, 4), 256, 0, stream>>>(nb[0], nb[1], off4, adj4,
        mB[0], mB[1], mB[2], mB[3], NSN);
    lgemm_k<1><<<dim3(gm, 2), 256, 0, stream>>>(nb[0], nb[1],
        mB[0], mB[1], mB[2], mB[3], wlB + (size_t)8 * 16384,
        wrcB + (size_t)4 * 16384, blc + 512, nb[2], nb[3], NSN);
  }
  // h3s = nb2, h3t = nb3

  // --- nodewise head precompute (consumes nb2,nb3) ---
  ushort* pS = shared4;
  ushort* pT = shared4 + 2 * NBE;
  gemmH_k<<<dim3(gm, 2, 2), 256, 0, stream>>>(nbase + 2 * NBE, Whead, biasHead, pS, pT);

  // --- permute ea into CSR order (nbase region dead after gemmH) ---
  ushort* eaB = nbase;
  eaperm_k<<<((EE * 8) + 255) / 256, 256, 0, stream>>>(edge_attr, adjE, eaB, EE);

  // --- fused edge head (CSR-ordered, barrier-free per-wave tiles) ---
  head_k<<<(EE + 63) / 64, 256, 0, stream>>>(pS, pT,
      adj4 + (size_t)2 * EE, colOf, adjE, eaB, w1eB, w2B,
      gate_w2, gate_b2, mlp_b2, mlp_w3, mlp_b3, out, EE);
}

// Round 15
// 791.131 us; speedup vs baseline: 1.0212x; 1.0212x over previous
//
#include <hip/hip_runtime.h>
#include <cmath>

#define NSN 50000
#define NTN 50000
#define EE  500000
#define NBE ((size_t)NSN * 128)
#define NPASS 2
#define PRNG 25000

using short8 = __attribute__((ext_vector_type(8))) short;
using f32x4  = __attribute__((ext_vector_type(4))) float;
#define MFMA16(a, b, c) __builtin_amdgcn_mfma_f32_16x16x32_bf16(a, b, c, 0, 0, 0)

__device__ __forceinline__ float  b2f(ushort u) { return __uint_as_float(((uint)u) << 16); }
__device__ __forceinline__ ushort f2b(float f) {
  uint x = __float_as_uint(f);
  uint r = x + 0x7FFFu + ((x >> 16) & 1u);
  return (ushort)(r >> 16);
}
__device__ __forceinline__ float blo(uint x) { return __uint_as_float(x << 16); }
__device__ __forceinline__ float bhi(uint x) { return __uint_as_float(x & 0xFFFF0000u); }
__device__ __forceinline__ uint  pk2(float a, float b) { return (uint)f2b(a) | ((uint)f2b(b) << 16); }

// ------------------------------------------------- all input/weight converts
__global__ void cvtall_k(const float* __restrict__ xs, const float* __restrict__ xt,
                         const float* __restrict__ wl,
                         const float* __restrict__ esw1, const float* __restrict__ esw2,
                         const float* __restrict__ etw1, const float* __restrict__ etw2,
                         ushort* __restrict__ xsB, ushort* __restrict__ xtB,
                         ushort* __restrict__ wlB, ushort* __restrict__ esw1B,
                         ushort* __restrict__ esw2B, ushort* __restrict__ etw1B,
                         ushort* __restrict__ etw2B) {
  int i = blockIdx.x * 256 + threadIdx.x;
  if (i < 3200000) { xsB[i] = f2b(xs[i]); return; }
  i -= 3200000;
  if (i < 3200000) {
    int r = i >> 6, k = i & 63;
    xtB[i] = (k < 48) ? f2b(xt[(size_t)r * 48 + k]) : (ushort)0;
    return;
  }
  i -= 3200000;
  if (i < 196608) { wlB[i] = f2b(wl[i]); return; }
  i -= 196608;
  if (i < 8192) { esw1B[i] = f2b(esw1[i]); return; }
  i -= 8192;
  if (i < 16384) { esw2B[i] = f2b(esw2[i]); return; }
  i -= 16384;
  if (i < 8192) {
    int r = i >> 6, k = i & 63;
    etw1B[i] = (k < 48) ? f2b(etw1[(size_t)r * 48 + k]) : (ushort)0;
    return;
  }
  i -= 8192;
  if (i < 16384) { etw2B[i] = f2b(etw2[i]); return; }
}

// ------------------------------------------------- combined wr + bias
__global__ void wrc_k(const float* __restrict__ wr, const float* __restrict__ bl,
                      ushort* __restrict__ wrcB, float* __restrict__ blc) {
  int z = blockIdx.y;
  int l = z >> 1, dd = z & 1;
  int r1 = dd ? 1 : 0, r2 = dd ? 2 : 3;
  int idx = blockIdx.x * 256 + threadIdx.x;
  if (idx < 16384) {
    wrcB[(size_t)z * 16384 + idx] =
        f2b(wr[(size_t)(l * 4 + r1) * 16384 + idx] + wr[(size_t)(l * 4 + r2) * 16384 + idx]);
    if (idx < 128)
      blc[z * 128 + idx] = bl[(l * 4 + r1) * 128 + idx] + bl[(l * 4 + r2) * 128 + idx];
  }
}

// ------------------------------------------------- head weight assembly
__global__ void headw_k(const float* __restrict__ gw1, const float* __restrict__ mw1,
                        const float* __restrict__ mw2, const float* __restrict__ gb1,
                        const float* __restrict__ mb1,
                        ushort* __restrict__ Whead, float* __restrict__ biasHead,
                        ushort* __restrict__ w1eB, ushort* __restrict__ w2B) {
  int idx = blockIdx.x * 256 + threadIdx.x;
  if (idx < 65536) {
    int z = idx >> 15, rr = (idx >> 7) & 255, c = idx & 127;
    float v = (rr < 128) ? gw1[(size_t)rr * 256 + z * 128 + c]
                         : mw1[(size_t)(rr - 128) * 160 + c];
    Whead[idx] = f2b(v);
  } else if (idx < 69632) {
    int i = idx - 65536;
    w1eB[i] = f2b(mw1[(size_t)(i >> 5) * 160 + 128 + (i & 31)]);
  } else if (idx < 77824) {
    int i = idx - 69632;
    w2B[i] = f2b(mw2[i]);
  } else if (idx < 78336) {
    int i = idx - 77824;
    int z = i >> 8, n = i & 255;
    biasHead[i] = (n < 128) ? (z ? 0.f : gb1[n]) : mb1[n - 128];
  }
}

// --------------------------------------------------------------- CSR build
__global__ void count4_k(const int* __restrict__ e0, const int* __restrict__ e1,
                         const int* __restrict__ e2, const int* __restrict__ e3,
                         int* __restrict__ cnt) {
  int rel = blockIdx.y;
  const int* col = (rel == 0 ? e0 : rel == 1 ? e1 : rel == 2 ? e2 : e3) + EE;
  int i = blockIdx.x * 256 + threadIdx.x;
  if (i < EE) atomicAdd(&cnt[rel * 50000 + col[i]], 1);
}

// hierarchical scan
__global__ __launch_bounds__(256) void scanA_k(const int* __restrict__ cnt,
                                               int* __restrict__ loc,
                                               int* __restrict__ bsum) {
  __shared__ int ws[4];
  int rel = blockIdx.y, b = blockIdx.x, t = threadIdx.x;
  const int* c = cnt + (size_t)rel * 50000;
  int base = b * 2048 + t * 8;
  int v[8], s = 0;
  #pragma unroll
  for (int i = 0; i < 8; ++i) {
    int idx = base + i;
    v[i] = (idx < 50000) ? c[idx] : 0;
    s += v[i];
  }
  int lane = t & 63, w = t >> 6;
  int x = s;
  #pragma unroll
  for (int d = 1; d < 64; d <<= 1) {
    int y = __shfl_up(x, d, 64);
    if (lane >= d) x += y;
  }
  if (lane == 63) ws[w] = x;
  __syncthreads();
  int add = 0;
  for (int ww = 0; ww < w; ++ww) add += ws[ww];
  int run = add + x - s;
  #pragma unroll
  for (int i = 0; i < 8; ++i) {
    int idx = base + i;
    run += v[i];
    if (idx < 50000) loc[(size_t)rel * 50000 + idx] = run;
  }
  if (t == 255) bsum[rel * 25 + b] = add + x;
}
__global__ void scanB_k(int* __restrict__ bsum) {
  int t = threadIdx.x;
  if (t < 4) {
    int s = 0;
    for (int b = 0; b < 25; ++b) {
      int v = bsum[t * 25 + b];
      bsum[t * 25 + b] = s;
      s += v;
    }
  }
}
// scanC also expands rel-2 per-position col (folded colof)
__global__ void scanC_k(const int* __restrict__ cnt, const int* __restrict__ loc,
                        const int* __restrict__ bsum, int* __restrict__ off,
                        int* __restrict__ cur, int* __restrict__ colOf) {
  int rel = blockIdx.y;
  int i = blockIdx.x * 256 + threadIdx.x;
  if (i < 50000) {
    int incl = loc[(size_t)rel * 50000 + i] + bsum[rel * 25 + i / 2048];
    int cntv = cnt[(size_t)rel * 50000 + i];
    off[(size_t)rel * 50001 + i + 1] = incl;
    cur[(size_t)rel * 50000 + i] = incl - cntv;
    if (i == 0) off[(size_t)rel * 50001] = 0;
    if (rel == 2) {
      for (int k = incl - cntv; k < incl; ++k) colOf[k] = i;
    }
  }
}

// range-partitioned fill; rel 2 also records original edge id
__global__ void fillP_k(const int* __restrict__ e0, const int* __restrict__ e1,
                        const int* __restrict__ e2, const int* __restrict__ e3,
                        int* __restrict__ cur, int* __restrict__ adj,
                        int* __restrict__ adjE, int pass) {
  int rel = blockIdx.y;
  const int* ei = rel == 0 ? e0 : rel == 1 ? e1 : rel == 2 ? e2 : e3;
  int e = blockIdx.x * 256 + threadIdx.x;
  if (e < EE) {
    int c = ei[EE + e];
    if (c >= pass * PRNG && c < (pass + 1) * PRNG) {
      int pos = atomicAdd(&cur[rel * 50000 + c], 1);
      adj[(size_t)rel * EE + pos] = ei[e];
      if (rel == 2) adjE[pos] = e;
    }
  }
}

// -------------------------------- permute ea into CSR order (+bf16 convert)
__global__ void eaperm_k(const float* __restrict__ ea, const int* __restrict__ adjE,
                         ushort* __restrict__ eaB, int E) {
  int idx = blockIdx.x * 256 + threadIdx.x;
  int pos = idx >> 3, q = idx & 7;
  if (pos < E) {
    int eid = adjE[pos];
    float4 v = *(const float4*)(ea + (size_t)eid * 32 + q * 4);
    ushort4 o;
    o.x = f2b(v.x); o.y = f2b(v.y); o.z = f2b(v.z); o.w = f2b(v.w);
    *(ushort4*)(eaB + (size_t)pos * 32 + q * 4) = o;
  }
}

// ------------------------------------------------------------- gather-mean
__global__ __launch_bounds__(256) void gather4_k(
    const ushort* __restrict__ hs, const ushort* __restrict__ ht,
    const int* __restrict__ off4, const int* __restrict__ adj4,
    ushort* __restrict__ m0, ushort* __restrict__ m1,
    ushort* __restrict__ m2, ushort* __restrict__ m3, int N) {
  int r = blockIdx.y;
  const ushort* src = (r == 0 || r == 2) ? hs : ht;
  ushort* dst = r == 0 ? m0 : (r == 1 ? m1 : (r == 2 ? m2 : m3));
  const int* off = off4 + r * 50001;
  const int* adj = adj4 + (size_t)r * EE;
  int t = threadIdx.x;
  int n = blockIdx.x * 4 + (t >> 6);
  if (n >= N) return;
  int lane = t & 63, g = lane >> 4, i = lane & 15;
  int s = off[n], e = off[n + 1];
  float a[8] = {};
  int k = s + g;
  for (; k + 4 < e; k += 8) {
    int r0 = adj[k], r1 = adj[k + 4];
    uint4 v0 = *(const uint4*)(src + (size_t)r0 * 128 + i * 8);
    uint4 v1 = *(const uint4*)(src + (size_t)r1 * 128 + i * 8);
    a[0] += blo(v0.x) + blo(v1.x); a[1] += bhi(v0.x) + bhi(v1.x);
    a[2] += blo(v0.y) + blo(v1.y); a[3] += bhi(v0.y) + bhi(v1.y);
    a[4] += blo(v0.z) + blo(v1.z); a[5] += bhi(v0.z) + bhi(v1.z);
    a[6] += blo(v0.w) + blo(v1.w); a[7] += bhi(v0.w) + bhi(v1.w);
  }
  if (k < e) {
    int r0 = adj[k];
    uint4 v = *(const uint4*)(src + (size_t)r0 * 128 + i * 8);
    a[0] += blo(v.x); a[1] += bhi(v.x);
    a[2] += blo(v.y); a[3] += bhi(v.y);
    a[4] += blo(v.z); a[5] += bhi(v.z);
    a[6] += blo(v.w); a[7] += bhi(v.w);
  }
  #pragma unroll
  for (int c = 0; c < 8; ++c) {
    a[c] += __shfl_xor(a[c], 16, 64);
    a[c] += __shfl_xor(a[c], 32, 64);
  }
  if (g == 0) {
    float inv = 1.f / (float)max(e - s, 1);
    uint4 o;
    o.x = pk2(a[0] * inv, a[1] * inv);
    o.y = pk2(a[2] * inv, a[3] * inv);
    o.z = pk2(a[4] * inv, a[5] * inv);
    o.w = pk2(a[6] * inv, a[7] * inv);
    *(uint4*)(dst + (size_t)n * 128 + i * 8) = o;
  }
}

// ------------------------------------------------------- shared GEMM body
template <int MODE>
__device__ __forceinline__ void gemm_body(
    ushort (*As)[40], ushort (*Ws)[40],
    const ushort* __restrict__ A, const ushort* __restrict__ W,
    const float* __restrict__ bias, ushort* __restrict__ C,
    int M, int K, int ldc, int m0) {
  int t = threadIdx.x;
  int lane = t & 63, w = t >> 6, wm = w >> 1, wn = w & 1;
  f32x4 zz = {0.f, 0.f, 0.f, 0.f};
  f32x4 acc[4][4];
  #pragma unroll
  for (int i = 0; i < 4; ++i)
    #pragma unroll
    for (int j = 0; j < 4; ++j) acc[i][j] = zz;
  for (int kb = 0; kb < K; kb += 32) {
    #pragma unroll
    for (int s = 0; s < 2; ++s) {
      int idx = t + s * 256;
      int r = idx >> 2, c = idx & 3;
      int gm = m0 + r;
      uint4 va = make_uint4(0, 0, 0, 0);
      if (gm < M) va = *(const uint4*)(A + (size_t)gm * K + kb + c * 8);
      *(uint4*)&As[r][c * 8] = va;
      *(uint4*)&Ws[r][c * 8] = *(const uint4*)(W + (size_t)r * K + kb + c * 8);
    }
    __syncthreads();
    short8 af[4], bf[4];
    #pragma unroll
    for (int mf = 0; mf < 4; ++mf)
      af[mf] = *(const short8*)&As[wm * 64 + mf * 16 + (lane & 15)][(lane >> 4) * 8];
    #pragma unroll
    for (int nf = 0; nf < 4; ++nf)
      bf[nf] = *(const short8*)&Ws[wn * 64 + nf * 16 + (lane & 15)][(lane >> 4) * 8];
    #pragma unroll
    for (int mf = 0; mf < 4; ++mf)
      #pragma unroll
      for (int nf = 0; nf < 4; ++nf) acc[mf][nf] = MFMA16(af[mf], bf[nf], acc[mf][nf]);
    __syncthreads();
  }
  int r0 = (lane >> 4) * 4, nin = lane & 15;
  #pragma unroll
  for (int mf = 0; mf < 4; ++mf)
    #pragma unroll
    for (int nf = 0; nf < 4; ++nf) {
      int n = wn * 64 + nf * 16 + nin;
      float bv = bias ? bias[n] : 0.f;
      #pragma unroll
      for (int i = 0; i < 4; ++i) {
        int gm = m0 + wm * 64 + mf * 16 + r0 + i;
        if (gm >= M) continue;
        float v = acc[mf][nf][i] + bv;
        if (MODE == 1) v = fmaxf(v, 0.f);
        C[(size_t)gm * ldc + n] = f2b(v);
      }
    }
}

// -------------------------------- fused 2-layer encoder (h1 kept in LDS)
__global__ __launch_bounds__(256) void encf_k(
    const ushort* __restrict__ A0, const ushort* __restrict__ A1,
    const ushort* __restrict__ W10, const ushort* __restrict__ W11,
    const ushort* __restrict__ W20, const ushort* __restrict__ W21,
    const float* __restrict__ b10, const float* __restrict__ b11,
    const float* __restrict__ b20, const float* __restrict__ b21,
    ushort* __restrict__ C0, ushort* __restrict__ C1, int M) {
  __shared__ alignas(16) ushort As[128][40];
  __shared__ alignas(16) ushort Ws[128][40];
  __shared__ alignas(16) ushort H1[128][136];
  int y = blockIdx.y;
  const ushort* A  = y ? A1 : A0;
  const ushort* W1 = y ? W11 : W10;
  const ushort* W2 = y ? W21 : W20;
  const float* b1 = y ? b11 : b10;
  const float* b2 = y ? b21 : b20;
  ushort* C = y ? C1 : C0;
  int t = threadIdx.x;
  int m0 = blockIdx.x * 128;
  int lane = t & 63, w = t >> 6, wm = w >> 1, wn = w & 1;
  f32x4 zz = {0.f, 0.f, 0.f, 0.f};
  f32x4 acc[4][4];
  #pragma unroll
  for (int i = 0; i < 4; ++i)
    #pragma unroll
    for (int j = 0; j < 4; ++j) acc[i][j] = zz;
  for (int kb = 0; kb < 64; kb += 32) {
    #pragma unroll
    for (int s = 0; s < 2; ++s) {
      int idx = t + s * 256;
      int r = idx >> 2, c = idx & 3;
      int gm = m0 + r;
      uint4 va = make_uint4(0, 0, 0, 0);
      if (gm < M) va = *(const uint4*)(A + (size_t)gm * 64 + kb + c * 8);
      *(uint4*)&As[r][c * 8] = va;
      *(uint4*)&Ws[r][c * 8] = *(const uint4*)(W1 + (size_t)r * 64 + kb + c * 8);
    }
    __syncthreads();
    short8 af[4], bf[4];
    #pragma unroll
    for (int mf = 0; mf < 4; ++mf)
      af[mf] = *(const short8*)&As[wm * 64 + mf * 16 + (lane & 15)][(lane >> 4) * 8];
    #pragma unroll
    for (int nf = 0; nf < 4; ++nf)
      bf[nf] = *(const short8*)&Ws[wn * 64 + nf * 16 + (lane & 15)][(lane >> 4) * 8];
    #pragma unroll
    for (int mf = 0; mf < 4; ++mf)
      #pragma unroll
      for (int nf = 0; nf < 4; ++nf) acc[mf][nf] = MFMA16(af[mf], bf[nf], acc[mf][nf]);
    __syncthreads();
  }
  {
    int r0 = (lane >> 4) * 4, nin = lane & 15;
    #pragma unroll
    for (int mf = 0; mf < 4; ++mf)
      #pragma unroll
      for (int nf = 0; nf < 4; ++nf) {
        int n = wn * 64 + nf * 16 + nin;
        float bv = b1[n];
        #pragma unroll
        for (int i = 0; i < 4; ++i)
          H1[wm * 64 + mf * 16 + r0 + i][n] = f2b(fmaxf(acc[mf][nf][i] + bv, 0.f));
      }
  }
  __syncthreads();
  #pragma unroll
  for (int i = 0; i < 4; ++i)
    #pragma unroll
    for (int j = 0; j < 4; ++j) acc[i][j] = zz;
  for (int kb = 0; kb < 128; kb += 32) {
    #pragma unroll
    for (int s = 0; s < 2; ++s) {
      int idx = t + s * 256;
      int r = idx >> 2, c = idx & 3;
      *(uint4*)&Ws[r][c * 8] = *(const uint4*)(W2 + (size_t)r * 128 + kb + c * 8);
    }
    __syncthreads();
    short8 af[4], bf[4];
    #pragma unroll
    for (int mf = 0; mf < 4; ++mf)
      af[mf] = *(const short8*)&H1[wm * 64 + mf * 16 + (lane & 15)][kb + (lane >> 4) * 8];
    #pragma unroll
    for (int nf = 0; nf < 4; ++nf)
      bf[nf] = *(const short8*)&Ws[wn * 64 + nf * 16 + (lane & 15)][(lane >> 4) * 8];
    #pragma unroll
    for (int mf = 0; mf < 4; ++mf)
      #pragma unroll
      for (int nf = 0; nf < 4; ++nf) acc[mf][nf] = MFMA16(af[mf], bf[nf], acc[mf][nf]);
    __syncthreads();
  }
  {
    int r0 = (lane >> 4) * 4, nin = lane & 15;
    #pragma unroll
    for (int mf = 0; mf < 4; ++mf)
      #pragma unroll
      for (int nf = 0; nf < 4; ++nf) {
        int n = wn * 64 + nf * 16 + nin;
        float bv = b2[n];
        #pragma unroll
        for (int i = 0; i < 4; ++i) {
          int gm = m0 + wm * 64 + mf * 16 + r0 + i;
          if (gm >= M) continue;
          C[(size_t)gm * 128 + n] = f2b(acc[mf][nf][i] + bv);
        }
      }
  }
}

__global__ __launch_bounds__(256) void gemmH_k(
    const ushort* Abase, const ushort* Whead, const float* biasHead,
    ushort* pS, ushort* pT) {
  __shared__ alignas(16) ushort As[128][40];
  __shared__ alignas(16) ushort Ws[128][40];
  int z = blockIdx.z, ny = blockIdx.y;
  gemm_body<0>(As, Ws, Abase + (size_t)z * NBE,
               Whead + ((size_t)z * 256 + ny * 128) * 128,
               biasHead + z * 256 + ny * 128,
               (z ? pT : pS) + ny * 128,
               NSN, 128, 256, blockIdx.x * 128);
}

// ---------------------------------- layer GEMM: 3 A-panels, both dst types
template <int RES>
__global__ __launch_bounds__(256) void lgemm_k(
    const ushort* __restrict__ hs, const ushort* __restrict__ ht,
    const ushort* __restrict__ m0, const ushort* __restrict__ m1,
    const ushort* __restrict__ m2, const ushort* __restrict__ m3,
    const ushort* __restrict__ wlL, const ushort* __restrict__ wrcL,
    const float* __restrict__ blcL,
    ushort* __restrict__ hsOut, ushort* __restrict__ htOut, int M) {
  __shared__ alignas(16) ushort As[128][40];
  __shared__ alignas(16) ushort Ws[128][40];
  int t = threadIdx.x;
  int y = blockIdx.y;
  int m0i = blockIdx.x * 128;
  const ushort* A0 = y ? m1 : m0;
  const ushort* A1 = y ? m2 : m3;
  const ushort* self = y ? ht : hs;
  const ushort* W0 = wlL + (size_t)(y ? 1 : 0) * 16384;
  const ushort* W1 = wlL + (size_t)(y ? 2 : 3) * 16384;
  const ushort* W2 = wrcL + (size_t)y * 16384;
  const float* bias = blcL + y * 128;
  ushort* C = y ? htOut : hsOut;

  int lane = t & 63, w = t >> 6, wm = w >> 1, wn = w & 1;
  f32x4 zz = {0.f, 0.f, 0.f, 0.f};
  f32x4 acc[4][4];
  #pragma unroll
  for (int i = 0; i < 4; ++i)
    #pragma unroll
    for (int j = 0; j < 4; ++j) acc[i][j] = zz;
  for (int p = 0; p < 3; ++p) {
    const ushort* A = p == 0 ? A0 : (p == 1 ? A1 : self);
    const ushort* Wp = p == 0 ? W0 : (p == 1 ? W1 : W2);
    for (int kb = 0; kb < 128; kb += 32) {
      #pragma unroll
      for (int s = 0; s < 2; ++s) {
        int idx = t + s * 256;
        int r = idx >> 2, c = idx & 3;
        int gm = m0i + r;
        uint4 va = make_uint4(0, 0, 0, 0);
        if (gm < M) va = *(const uint4*)(A + (size_t)gm * 128 + kb + c * 8);
        *(uint4*)&As[r][c * 8] = va;
        *(uint4*)&Ws[r][c * 8] = *(const uint4*)(Wp + (size_t)r * 128 + kb + c * 8);
      }
      __syncthreads();
      short8 af[4], bf[4];
      #pragma unroll
      for (int mf = 0; mf < 4; ++mf)
        af[mf] = *(const short8*)&As[wm * 64 + mf * 16 + (lane & 15)][(lane >> 4) * 8];
      #pragma unroll
      for (int nf = 0; nf < 4; ++nf)
        bf[nf] = *(const short8*)&Ws[wn * 64 + nf * 16 + (lane & 15)][(lane >> 4) * 8];
      #pragma unroll
      for (int mf = 0; mf < 4; ++mf)
        #pragma unroll
        for (int nf = 0; nf < 4; ++nf) acc[mf][nf] = MFMA16(af[mf], bf[nf], acc[mf][nf]);
      __syncthreads();
    }
  }
  int r0 = (lane >> 4) * 4, nin = lane & 15;
  #pragma unroll
  for (int mf = 0; mf < 4; ++mf)
    #pragma unroll
    for (int nf = 0; nf < 4; ++nf) {
      int n = wn * 64 + nf * 16 + nin;
      float bv = bias[n];
      #pragma unroll
      for (int i = 0; i < 4; ++i) {
        int gm = m0i + wm * 64 + mf * 16 + r0 + i;
        if (gm >= M) continue;
        float v = 0.5f * (acc[mf][nf][i] + bv);
        if (RES) v += b2f(self[(size_t)gm * 128 + n]);
        C[(size_t)gm * 128 + n] = f2b(fmaxf(v, 0.f));
      }
    }
}

// ---------------------------------------------------------------- edge head
// R8 measured-best variant: CSR-ordered edges; ea pre-permuted (sequential
// bf16 loads); block-wide phases; inline Phase-G loads (no prefetch regs).
__global__ __launch_bounds__(256) void head_k(
    const ushort* __restrict__ pS, const ushort* __restrict__ pT,
    const int* __restrict__ erowA, const int* __restrict__ ecolA,
    const int* __restrict__ eidA, const ushort* __restrict__ eaB,
    const ushort* __restrict__ w1eB, const ushort* __restrict__ w2B,
    const float* __restrict__ gw2, const float* __restrict__ gb2p,
    const float* __restrict__ mb2, const float* __restrict__ mw3,
    const float* __restrict__ mb3, float* __restrict__ out, int E) {
  __shared__ alignas(16) ushort h1s[64][136];    // eat -> h1 -> (aliased) h2F
  __shared__ int er[64], ec[64], eidS[64];
  __shared__ alignas(16) float gw2s[128];
  __shared__ alignas(16) float mw3s[128];
  __shared__ float mb2s[64];
  float (*h2F)[68] = (float(*)[68])&h1s[0][0];

  // bijective XCD swizzle (nwg % 8 != 0 safe)
  int nwg = gridDim.x;
  int bid = blockIdx.x;
  int q = nwg >> 3, r = nwg & 7;
  int xcd = bid & 7, sub = bid >> 3;
  int swz = (xcd < r ? xcd * (q + 1) : r * (q + 1) + (xcd - r) * q) + sub;
  int e0 = swz * 64;

  int t = threadIdx.x;
  if (t < 64) {
    int p = e0 + t;
    er[t] = (p < E) ? erowA[p] : 0;
    eidS[t] = (p < E) ? eidA[p] : -1;
    mb2s[t] = mb2[t];
  } else if (t < 128) {
    int p = e0 + (t - 64);
    ec[t - 64] = (p < E) ? ecolA[p] : 0;
  }
  if (t < 128) gw2s[t] = gw2[t];
  else mw3s[t - 128] = mw3[t - 128];
  __syncthreads();
  int lane = t & 63, w = t >> 6;
  // Phase E: eat = ea @ w1e^T (M=64, N=128, K=32) -> h1s; A straight from eaB
  {
    int p = e0 + w * 16 + (lane & 15);
    short8 a = {};
    if (p < E) a = *(const short8*)(eaB + (size_t)p * 32 + (lane >> 4) * 8);
    int ebase = w * 16 + (lane >> 4) * 4;
    #pragma unroll
    for (int nf = 0; nf < 8; ++nf) {
      short8 b = *(const short8*)(w1eB + (size_t)(nf * 16 + (lane & 15)) * 32 + (lane >> 4) * 8);
      f32x4 cz = {0.f, 0.f, 0.f, 0.f};
      cz = MFMA16(a, b, cz);
      int jj = nf * 16 + (lane & 15);
      #pragma unroll
      for (int i = 0; i < 4; ++i) h1s[ebase + i][jj] = f2b(cz[i]);
    }
  }
  __syncthreads();
  // Phase G: gate + convex combine + eat (in-place RMW) + relu -> h1s
  {
    int el = lane >> 2, qq = lane & 3, e = w * 16 + el;
    int j0 = qq * 32;
    const ushort* ps = pS + (size_t)er[e] * 256;
    const ushort* pt = pT + (size_t)ec[e] * 256;
    float dot = 0.f;
    #pragma unroll
    for (int cc = 0; cc < 4; ++cc) {
      int j = j0 + cc * 8;
      uint4 ga = *(const uint4*)(ps + j);
      uint4 gb = *(const uint4*)(pt + j);
      const float* gp = &gw2s[j];
      float h;
      h = fmaxf(blo(ga.x) + blo(gb.x), 0.f); dot = fmaf(h, gp[0], dot);
      h = fmaxf(bhi(ga.x) + bhi(gb.x), 0.f); dot = fmaf(h, gp[1], dot);
      h = fmaxf(blo(ga.y) + blo(gb.y), 0.f); dot = fmaf(h, gp[2], dot);
      h = fmaxf(bhi(ga.y) + bhi(gb.y), 0.f); dot = fmaf(h, gp[3], dot);
      h = fmaxf(blo(ga.z) + blo(gb.z), 0.f); dot = fmaf(h, gp[4], dot);
      h = fmaxf(bhi(ga.z) + bhi(gb.z), 0.f); dot = fmaf(h, gp[5], dot);
      h = fmaxf(blo(ga.w) + blo(gb.w), 0.f); dot = fmaf(h, gp[6], dot);
      h = fmaxf(bhi(ga.w) + bhi(gb.w), 0.f); dot = fmaf(h, gp[7], dot);
    }
    dot += __shfl_xor(dot, 1, 64);
    dot += __shfl_xor(dot, 2, 64);
    float g = 1.f / (1.f + __expf(-(dot + gb2p[0])));
    float om = 1.f - g;
    #pragma unroll
    for (int cc = 0; cc < 4; ++cc) {
      int j = j0 + cc * 8;
      uint4 uu = *(const uint4*)(ps + 128 + j);
      uint4 vv = *(const uint4*)(pt + 128 + j);
      uint4 ee = *(const uint4*)&h1s[e][j];
      uint o0 = pk2(fmaxf(fmaf(g, blo(uu.x), om * blo(vv.x)) + blo(ee.x), 0.f),
                    fmaxf(fmaf(g, bhi(uu.x), om * bhi(vv.x)) + bhi(ee.x), 0.f));
      uint o1 = pk2(fmaxf(fmaf(g, blo(uu.y), om * blo(vv.y)) + blo(ee.y), 0.f),
                    fmaxf(fmaf(g, bhi(uu.y), om * bhi(vv.y)) + bhi(ee.y), 0.f));
      uint o2 = pk2(fmaxf(fmaf(g, blo(uu.z), om * blo(vv.z)) + blo(ee.z), 0.f),
                    fmaxf(fmaf(g, bhi(uu.z), om * bhi(vv.z)) + bhi(ee.z), 0.f));
      uint o3 = pk2(fmaxf(fmaf(g, blo(uu.w), om * blo(vv.w)) + blo(ee.w), 0.f),
                    fmaxf(fmaf(g, bhi(uu.w), om * bhi(vv.w)) + bhi(ee.w), 0.f));
      *(uint4*)&h1s[e][j] = make_uint4(o0, o1, o2, o3);
    }
  }
  __syncthreads();
  // Phase H: h2 = relu(h1 @ w2^T + b2)
  {
    f32x4 zz = {0.f, 0.f, 0.f, 0.f};
    f32x4 acc[4] = {zz, zz, zz, zz};
    #pragma unroll
    for (int ks = 0; ks < 4; ++ks) {
      short8 a = *(const short8*)&h1s[w * 16 + (lane & 15)][ks * 32 + (lane >> 4) * 8];
      #pragma unroll
      for (int nf = 0; nf < 4; ++nf) {
        short8 b = *(const short8*)(w2B + (size_t)(nf * 16 + (lane & 15)) * 128 + ks * 32 + (lane >> 4) * 8);
        acc[nf] = MFMA16(a, b, acc[nf]);
      }
    }
    __syncthreads();
    int ebase = w * 16 + (lane >> 4) * 4;
    #pragma unroll
    for (int nf = 0; nf < 4; ++nf) {
      int n = nf * 16 + (lane & 15);
      #pragma unroll
      for (int i = 0; i < 4; ++i)
        h2F[ebase + i][n] = fmaxf(acc[nf][i] + mb2s[n], 0.f);
    }
  }
  __syncthreads();
  // Phase O: out scattered by original edge id
  if (t < 128) {
    int e = t >> 1, o = t & 1;
    int eid = eidS[e];
    if (eid >= 0) {
      float s = mb3[o];
      #pragma unroll
      for (int kk = 0; kk < 64; kk += 4) {
        float4 hv = *(const float4*)&h2F[e][kk];
        float4 wv = *(const float4*)&mw3s[o * 64 + kk];
        s = fmaf(hv.x, wv.x, s); s = fmaf(hv.y, wv.y, s);
        s = fmaf(hv.z, wv.z, s); s = fmaf(hv.w, wv.w, s);
      }
      out[(size_t)eid * 2 + o] = s;
    }
  }
}

// ------------------------------------------------------------------- launch
extern "C" void kernel_launch(void* const* d_in, const int* in_sizes, int n_in,
                              void* d_out, int out_size, void* d_ws, size_t ws_size,
                              hipStream_t stream) {
  const float* x_source = (const float*)d_in[0];
  const float* x_target = (const float*)d_in[1];
  const float* edge_attr = (const float*)d_in[2];
  const float* enc_s_w1 = (const float*)d_in[3];
  const float* enc_s_b1 = (const float*)d_in[4];
  const float* enc_s_w2 = (const float*)d_in[5];
  const float* enc_s_b2 = (const float*)d_in[6];
  const float* enc_t_w1 = (const float*)d_in[7];
  const float* enc_t_b1 = (const float*)d_in[8];
  const float* enc_t_w2 = (const float*)d_in[9];
  const float* enc_t_b2 = (const float*)d_in[10];
  const float* conv_wl = (const float*)d_in[11];
  const float* conv_bl = (const float*)d_in[12];
  const float* conv_wr = (const float*)d_in[13];
  const float* gate_w1 = (const float*)d_in[14];
  const float* gate_b1 = (const float*)d_in[15];
  const float* gate_w2 = (const float*)d_in[16];
  const float* gate_b2 = (const float*)d_in[17];
  const float* mlp_w1 = (const float*)d_in[18];
  const float* mlp_b1 = (const float*)d_in[19];
  const float* mlp_w2 = (const float*)d_in[20];
  const float* mlp_b2 = (const float*)d_in[21];
  const float* mlp_w3 = (const float*)d_in[22];
  const float* mlp_b3 = (const float*)d_in[23];
  const int* ei[4] = {(const int*)d_in[24], (const int*)d_in[25],
                      (const int*)d_in[26], (const int*)d_in[27]};  // 0=ss,1=tt,2=st,3=ts
  float* out = (float*)d_out;

  char* wsp = (char*)d_ws;
  size_t off = 0;
  auto alloc = [&](size_t bytes) {
    char* p = wsp + off;
    off += (bytes + 255) & ~(size_t)255;
    return p;
  };
  ushort* nbase = (ushort*)alloc(4 * NBE * 2);
  ushort* nb[4];
  for (int i = 0; i < 4; ++i) nb[i] = nbase + (size_t)i * NBE;
  ushort* shared4 = (ushort*)alloc(4 * NBE * 2);
  ushort* mB[4];
  for (int i = 0; i < 4; ++i) mB[i] = shared4 + (size_t)i * NBE;
  int* adj4 = (int*)alloc((size_t)4 * EE * 4);
  int* off4 = (int*)alloc(4 * 50001 * 4);
  int* cur4 = (int*)alloc(4 * 50000 * 4);
  int* cnt4 = (int*)alloc(4 * 50000 * 4);
  int* bsum = (int*)alloc(128 * 4);
  ushort* xsB = (ushort*)alloc((size_t)NSN * 64 * 2);   // dead after encf -> adjE
  ushort* xtB = (ushort*)alloc((size_t)NTN * 64 * 2);   // dead after encf -> colOf
  ushort* esw1B = (ushort*)alloc(128 * 64 * 2);
  ushort* esw2B = (ushort*)alloc(128 * 128 * 2);
  ushort* etw1B = (ushort*)alloc(128 * 64 * 2);
  ushort* etw2B = (ushort*)alloc(128 * 128 * 2);
  ushort* wlB = (ushort*)alloc((size_t)12 * 16384 * 2);
  ushort* wrcB = (ushort*)alloc((size_t)6 * 16384 * 2);
  float* blc = (float*)alloc(6 * 128 * 4);
  ushort* Whead = (ushort*)alloc((size_t)2 * 256 * 128 * 2);
  float* biasHead = (float*)alloc(2 * 256 * 4);
  ushort* w1eB = (ushort*)alloc(128 * 32 * 2);
  ushort* w2B = (ushort*)alloc(64 * 128 * 2);

  // --- conversions / weight assembly / fused encoders (frees xsB/xtB) ---
  cvtall_k<<<(6645760 + 255) / 256, 256, 0, stream>>>(
      x_source, x_target, conv_wl, enc_s_w1, enc_s_w2, enc_t_w1, enc_t_w2,
      xsB, xtB, wlB, esw1B, esw2B, etw1B, etw2B);
  wrc_k<<<dim3(64, 6), 256, 0, stream>>>(conv_wr, conv_bl, wrcB, blc);
  headw_k<<<307, 256, 0, stream>>>(gate_w1, mlp_w1, mlp_w2, gate_b1, mlp_b1,
                                   Whead, biasHead, w1eB, w2B);
  int gm = (NSN + 127) / 128;
  encf_k<<<dim3(gm, 2), 256, 0, stream>>>(xsB, xtB, esw1B, etw1B, esw2B, etw2B,
      enc_s_b1, enc_t_b1, enc_s_b2, enc_t_b2, nb[0], nb[1], NSN);

  // --- CSR build (adjE/colOf overlay dead xsB/xtB) ---
  int* adjE = (int*)xsB;
  int* colOf = (int*)xtB;
  hipMemsetAsync(cnt4, 0, 4 * 50000 * sizeof(int), stream);
  int cb = (EE + 255) / 256;
  count4_k<<<dim3(cb, 4), 256, 0, stream>>>(ei[0], ei[1], ei[2], ei[3], cnt4);
  scanA_k<<<dim3(25, 4), 256, 0, stream>>>(cnt4, cur4, bsum);
  scanB_k<<<1, 64, 0, stream>>>(bsum);
  scanC_k<<<dim3((50000 + 255) / 256, 4), 256, 0, stream>>>(cnt4, cur4, bsum, off4,
                                                            cur4, colOf);
  for (int p = 0; p < NPASS; ++p)
    fillP_k<<<dim3(cb, 4), 256, 0, stream>>>(ei[0], ei[1], ei[2], ei[3], cur4, adj4, adjE, p);

  // --- 3 hetero layers: (0,1)->(2,3)->(0,1)->(2,3) ---
  int gb = (NSN + 3) / 4;
  {
    gather4_k<<<dim3(gb, 4), 256, 0, stream>>>(nb[0], nb[1], off4, adj4,
        mB[0], mB[1], mB[2], mB[3], NSN);
    lgemm_k<0><<<dim3(gm, 2), 256, 0, stream>>>(nb[0], nb[1],
        mB[0], mB[1], mB[2], mB[3], wlB, wrcB, blc, nb[2], nb[3], NSN);
    gather4_k<<<dim3(gb, 4), 256, 0, stream>>>(nb[2], nb[3], off4, adj4,
        mB[0], mB[1], mB[2], mB[3], NSN);
    lgemm_k<1><<<dim3(gm, 2), 256, 0, stream>>>(nb[2], nb[3],
        mB[0], mB[1], mB[2], mB[3], wlB + (size_t)4 * 16384,
        wrcB + (size_t)2 * 16384, blc + 256, nb[0], nb[1], NSN);
    gather4_k<<<dim3(gb, 4), 256, 0, stream>>>(nb[0], nb[1], off4, adj4,
        mB[0], mB[1], mB[2], mB[3], NSN);
    lgemm_k<1><<<dim3(gm, 2), 256, 0, stream>>>(nb[0], nb[1],
        mB[0], mB[1], mB[2], mB[3], wlB + (size_t)8 * 16384,
        wrcB + (size_t)4 * 16384, blc + 512, nb[2], nb[3], NSN);
  }
  // h3s = nb2, h3t = nb3

  // --- nodewise head precompute (consumes nb2,nb3) ---
  ushort* pS = shared4;
  ushort* pT = shared4 + 2 * NBE;
  gemmH_k<<<dim3(gm, 2, 2), 256, 0, stream>>>(nbase + 2 * NBE, Whead, biasHead, pS, pT);

  // --- permute ea into CSR order (nbase region dead after gemmH) ---
  ushort* eaB = nbase;
  eaperm_k<<<((EE * 8) + 255) / 256, 256, 0, stream>>>(edge_attr, adjE, eaB, EE);

  // --- fused edge head (CSR-ordered, sequential eaB, R8-best structure) ---
  head_k<<<(EE + 63) / 64, 256, 0, stream>>>(pS, pT,
      adj4 + (size_t)2 * EE, colOf, adjE, eaB, w1eB, w2B,
      gate_w2, gate_b2, mlp_b2, mlp_w3, mlp_b3, out, EE);
}